// Round 1
// baseline (224.771 us; speedup 1.0000x reference)
//
#include <hip/hip_runtime.h>
#include <hip/hip_bf16.h>

#define B_  16
#define G_  4
#define CG  64
#define H_  64
#define W_  64
#define KK  9
#define HW  (H_ * W_)
#define IP  72            // padded i-stride (shorts) for sT rows: 144 B
#define PD  68            // padded spatial dim (64 + 2 each side)
#define XSLICE (PD * PD * CG)   // shorts per (b,g) slice of xTpad

typedef short  short8  __attribute__((ext_vector_type(8)));
typedef float  f32x4   __attribute__((ext_vector_type(4)));
typedef float  f32x16  __attribute__((ext_vector_type(16)));

__device__ __forceinline__ short f2bf(float v) {
    __hip_bfloat16 hb = __float2bfloat16(v);
    short s;
    __builtin_memcpy(&s, &hb, 2);
    return s;
}

// unpack a u32 holding two bf16 (ch 2j low, 2j+1 high) into float2
__device__ __forceinline__ float2 up2(unsigned int u) {
    union { unsigned int i; float f; } lo, hi;
    lo.i = u << 16;
    hi.i = u & 0xffff0000u;
    return make_float2(lo.f, hi.f);
}

// bilinear combine of 2 packed channels, repacked to 2 bf16 in a u32
__device__ __forceinline__ unsigned int interp2(unsigned int c00, unsigned int c01,
                                                unsigned int c10, unsigned int c11,
                                                float2 w00, float2 w01,
                                                float2 w10, float2 w11) {
    float2 r = up2(c00) * w00 + up2(c01) * w01 + up2(c10) * w10 + up2(c11) * w11;
    __hip_bfloat162 h = __float22bfloat162_rn(r);
    unsigned int o;
    __builtin_memcpy(&o, &h, 4);
    return o;
}

// ---------------------------------------------------------------------------
// Merged prep kernel, re-tiled for memory-level parallelism.
//  blocks [0, 1024): interior x transpose. Block = (bg, 4-row y-tile).
//    Reads 64 KB (16 float4/thread in flight), converts to packed bf16 in
//    registers, stages in padded LDS (row stride 33 words => conflict-free
//    column reads), writes xTpad[bg][yp][xp][i] with zeroed xp borders.
//  blocks [1024, 1088): y-border zero rows (yp in {0,1,66,67}) per bg.
//  blocks [1088, +864): weight prep (unchanged layouts)
//   dwA32[g][k][mt][step][q2][o][e] bf16 = def_w[g][mt*32+o][i=step*16+q2*8+e][k]
//   owA  [g][s][tm][q][jj][e]  bf16 = off_w[g][j=tm*16+jj][(s&1)*32+q*8+e][s>>1]
// ---------------------------------------------------------------------------
__global__ __launch_bounds__(256)
void prep_all(const float* __restrict__ x,
              const float* __restrict__ off_w,
              const float* __restrict__ def_w,
              short* __restrict__ xTpad,
              short* __restrict__ dwA32,
              short* __restrict__ owA)
{
    const int blk = blockIdx.x;
    const int t   = threadIdx.x;

    if (blk < 1024) {
        const int bg = blk >> 4;
        const int y0 = (blk & 15) * 4;

        __shared__ unsigned int sBw[4 * CG * 33];   // 33792 B, bf16x2 packed, padded

        const float* src = x + (size_t)bg * CG * HW + (size_t)y0 * W_;
        const int i  = t >> 2;          // channel 0..63
        const int x0 = (t & 3) * 16;    // col base 0/16/32/48

        // ---- load phase: 16 independent float4 loads per thread ----
        float4 v[4][4];
#pragma unroll
        for (int r = 0; r < 4; r++) {
            const float* sp = src + (size_t)i * HW + r * W_ + x0;
#pragma unroll
            for (int c = 0; c < 4; c++) v[r][c] = ((const float4*)sp)[c];
        }

        // ---- convert + stage (packed bf16x2, padded row stride 33 words) ----
#pragma unroll
        for (int r = 0; r < 4; r++) {
#pragma unroll
            for (int c = 0; c < 4; c++) {
                __hip_bfloat162 h0 = __float22bfloat162_rn(make_float2(v[r][c].x, v[r][c].y));
                __hip_bfloat162 h1 = __float22bfloat162_rn(make_float2(v[r][c].z, v[r][c].w));
                unsigned int u0, u1;
                __builtin_memcpy(&u0, &h0, 4);
                __builtin_memcpy(&u1, &h1, 4);
                const int base = (r * CG + i) * 33 + ((x0 + 4 * c) >> 1);
                sBw[base]     = u0;
                sBw[base + 1] = u1;
            }
        }
        __syncthreads();

        // ---- transpose-out phase: 16B stores, column reads hit 8 banks ----
        const short* sBs = (const short*)sBw;
        short* dst = xTpad + (size_t)bg * XSLICE;
#pragma unroll
        for (int r = 0; r < 4; r++) {
            const int yp = y0 + 2 + r;
            for (int task = t; task < PD * 8; task += 256) {
                const int ich = task & 7;
                const int xp  = task >> 3;
                const int xx  = xp - 2;
                short8 o = {0, 0, 0, 0, 0, 0, 0, 0};
                if ((unsigned)xx < (unsigned)W_) {
#pragma unroll
                    for (int e = 0; e < 8; e++)
                        o[e] = sBs[(r * CG + ich * 8 + e) * 66 + xx];
                }
                *(short8*)(dst + ((size_t)yp * PD + xp) * CG + ich * 8) = o;
            }
        }
        return;
    }

    if (blk < 1088) {
        // y-border zero rows: yp in {0,1} and {66,67}
        const int bg = blk - 1024;
        short* dstb = xTpad + (size_t)bg * XSLICE;
        const int4 z = {0, 0, 0, 0};
        int4* d0 = (int4*)(dstb);
        int4* d1 = (int4*)(dstb + (size_t)66 * PD * CG);
        const int n16 = (2 * PD * CG * 2) / 16;   // 1088 int4 per 2-row band
        for (int c = t; c < n16; c += 256) { d0[c] = z; d1[c] = z; }
        return;
    }

    // ---- weights part (unchanged) ----
    const int tid = (blk - 1088) * 256 + t;
    const int ndw = G_ * KK * 4096;               // 147456
    const int now = G_ * 18 * 2 * 4 * 16 * 8;     // 73728
    if (tid < ndw) {
        const int e    = tid & 7;
        const int o    = (tid >> 3) & 31;
        const int q2   = (tid >> 8) & 1;
        const int step = (tid >> 9) & 3;
        const int mt   = (tid >> 11) & 1;
        const int gk   = tid >> 12;
        const int k    = gk % KK;
        const int g    = gk / KK;
        const int oo   = mt * 32 + o;
        const int i    = step * 16 + q2 * 8 + e;
        dwA32[tid] = f2bf(def_w[((g * CG + oo) * CG + i) * KK + k]);
    } else if (tid < ndw + now) {
        const int t2 = tid - ndw;
        const int e  = t2 & 7;
        const int jj = (t2 >> 3) & 15;
        const int q  = (t2 >> 7) & 3;
        const int tm = (t2 >> 9) & 1;
        const int gs = t2 >> 10;
        const int s  = gs % 18;
        const int g  = gs / 18;
        const int j  = tm * 16 + jj;
        const int rc = s >> 1;
        const int i  = (s & 1) * 32 + q * 8 + e;
        owA[t2] = (j < 18) ? f2bf(off_w[((g * 18 + j) * CG + i) * KK + rc]) : (short)0;
    }
}

// ---------------------------------------------------------------------------
// Main fused kernel. Block = (b, g, h) with XCD swizzle. 256 threads, 4 waves.
//  Phase A: offset conv via MFMA 16x16x32 (per spatial tap: 1 addr calc, 2
//           b-frag loads in flight, 4 MFMAs), coords -> pcs[9][64] float2.
//  Phase B: per tap: 16B-wide bf16 gather from xTpad -> sT (double-buffered,
//           packed float2 interpolation), einsum via MFMA 32x32x16.
// ---------------------------------------------------------------------------
__global__ __launch_bounds__(256, 7)
void deform_main(const short* __restrict__ xTpad,
                 const float* __restrict__ off_b,
                 const float* __restrict__ def_b,
                 const short* __restrict__ dwA32,
                 const short* __restrict__ owA,
                 float* __restrict__ out)
{
    const int raw = blockIdx.x;
    const int r8  = raw & 7;
    const int h   = (raw >> 3) & 63;
    const int q8  = raw >> 9;
    const int bg  = q8 * 8 + r8;
    const int b   = bg >> 2;
    const int g   = bg & 3;

    __shared__ float2 pcs[KK][64];          // .x = padded py, .y = padded px
    __shared__ short  sT[2][64 * IP];

    const int t    = threadIdx.x;
    const int lane = t & 63;
    const int p    = t >> 6;          // wave id 0..3
    const int nn   = lane & 15;
    const int q    = lane >> 4;

    const short* xb = xTpad + (size_t)bg * XSLICE;

    // ---------------- Phase A: offset conv (MFMA 16x16x32) ----------------
    {
        const short* owAg = owA + g * 18 * 1024;
        f32x4 oa0 = {0.f, 0.f, 0.f, 0.f};
        f32x4 oa1 = {0.f, 0.f, 0.f, 0.f};
#pragma unroll
        for (int rc = 0; rc < 9; rc++) {
            const int rr = rc / 3;
            const int cc = rc % 3;
            const short* cp = xb + ((h + rr + 1) * PD + (p * 16 + nn + cc + 1)) * CG + q * 8;
            const short8 b0 = *(const short8*)cp;          // s = 2rc   (ih=0)
            const short8 b1 = *(const short8*)(cp + 32);   // s = 2rc+1 (ih=32)
            const int s0 = rc * 2, s1 = rc * 2 + 1;
            const short8 a00 = *(const short8*)(owAg + ((s0 * 2 + 0) * 4 + q) * 128 + nn * 8);
            const short8 a01 = *(const short8*)(owAg + ((s0 * 2 + 1) * 4 + q) * 128 + nn * 8);
            const short8 a10 = *(const short8*)(owAg + ((s1 * 2 + 0) * 4 + q) * 128 + nn * 8);
            const short8 a11 = *(const short8*)(owAg + ((s1 * 2 + 1) * 4 + q) * 128 + nn * 8);
            oa0 = __builtin_amdgcn_mfma_f32_16x16x32_bf16(a00, b0, oa0, 0, 0, 0);
            oa1 = __builtin_amdgcn_mfma_f32_16x16x32_bf16(a01, b0, oa1, 0, 0, 0);
            oa0 = __builtin_amdgcn_mfma_f32_16x16x32_bf16(a10, b1, oa0, 0, 0, 0);
            oa1 = __builtin_amdgcn_mfma_f32_16x16x32_bf16(a11, b1, oa1, 0, 0, 0);
        }
        // C layout: col = nn (w within tile), row = q*4 + reg (j)
        const int n = p * 16 + nn;
#pragma unroll
        for (int reg = 0; reg < 4; reg++) {
            const int j  = q * 4 + reg;
            const int kk = j >> 1;
            const float v = oa0[reg] + off_b[g * 18 + j];
            if ((j & 1) == 0) pcs[kk][n].x = v + (float)(kk / 3) + (float)(h + 1);
            else              pcs[kk][n].y = v + (float)(kk % 3) + (float)(n + 1);
        }
        if (q == 0) {
            pcs[8][n].x = oa1[0] + off_b[g * 18 + 16] + 2.0f + (float)(h + 1);
            pcs[8][n].y = oa1[1] + off_b[g * 18 + 17] + 2.0f + (float)(n + 1);
        }
        // each wave reads only its own tile's coords in the gather: no barrier
    }

    // ---------------- Phase B: gather + einsum, double-buffered ----------------
    const int mt  = p >> 1;           // einsum output 32-row tile
    const int nt  = p & 1;            // einsum output 32-col tile
    const int n31 = lane & 31;
    const int q2  = lane >> 5;

    f32x16 acc = {0.f};
    const short* dwg = dwA32 + g * KK * 4096;

    const int posL  = lane >> 3;      // 0..7: position within 8-group
    const int chidx = lane & 7;       // 8-channel chunk

    // gather of one tap into buffer sTb: 8 lanes/pos, 8 ch/lane, 16B loads
    auto gather_tap = [&](int k, short* __restrict__ sTb) {
#pragma unroll
        for (int it = 0; it < 2; it++) {
            const int pos = p * 16 + it * 8 + posL;
            const float2 pc = pcs[k][pos];
            const float yf = floorf(pc.x);
            const float xf = floorf(pc.y);
            const float wy = pc.x - yf;
            const float wx = pc.y - xf;
            int y0 = (int)yf;
            int x0 = (int)xf;
            y0 = (y0 < 0) ? 0 : ((y0 > 66) ? 66 : y0);
            x0 = (x0 < 0) ? 0 : ((x0 > 66) ? 66 : x0);
            const short* cp = xb + (y0 * PD + x0) * CG + chidx * 8;
            const uint4 c00 = *(const uint4*)cp;
            const uint4 c01 = *(const uint4*)(cp + CG);
            const uint4 c10 = *(const uint4*)(cp + PD * CG);
            const uint4 c11 = *(const uint4*)(cp + PD * CG + CG);
            const float a00 = (1.0f - wy) * (1.0f - wx);
            const float a01 = (1.0f - wy) * wx;
            const float a10 = wy * (1.0f - wx);
            const float a11 = wy * wx;
            const float2 w00 = make_float2(a00, a00);
            const float2 w01 = make_float2(a01, a01);
            const float2 w10 = make_float2(a10, a10);
            const float2 w11 = make_float2(a11, a11);
            uint4 ov;
            ov.x = interp2(c00.x, c01.x, c10.x, c11.x, w00, w01, w10, w11);
            ov.y = interp2(c00.y, c01.y, c10.y, c11.y, w00, w01, w10, w11);
            ov.z = interp2(c00.z, c01.z, c10.z, c11.z, w00, w01, w10, w11);
            ov.w = interp2(c00.w, c01.w, c10.w, c11.w, w00, w01, w10, w11);
            *(uint4*)&sTb[pos * IP + chidx * 8] = ov;
        }
    };

    // einsum of one tap from buffer sTb (MFMA 32x32x16)
    auto einsum_tap = [&](int k, const short* __restrict__ sTb) {
        const short* dwk = dwg + k * 4096;
#pragma unroll
        for (int step = 0; step < 4; step++) {
            const short8 af = *(const short8*)(dwk + ((mt * 4 + step) * 2 + q2) * 256 + n31 * 8);
            const short8 bf = *(const short8*)&sTb[(nt * 32 + n31) * IP + step * 16 + q2 * 8];
            acc = __builtin_amdgcn_mfma_f32_32x32x16_bf16(af, bf, acc, 0, 0, 0);
        }
    };

    gather_tap(0, &sT[0][0]);
    __syncthreads();
    for (int k = 0; k < KK; k++) {
        if (k < KK - 1) gather_tap(k + 1, &sT[(k + 1) & 1][0]);
        einsum_tap(k, &sT[k & 1][0]);
        __syncthreads();
    }

    // ---------------- epilogue ----------------
    // C/D 32x32 layout: col = lane&31, row = (reg&3) + 8*(reg>>2) + 4*q2
    float* outb = out + (size_t)(b * 256 + g * 64) * HW + h * W_;
    const int n = nt * 32 + n31;
#pragma unroll
    for (int reg = 0; reg < 16; reg++) {
        const int o = mt * 32 + (reg & 3) + 8 * (reg >> 2) + 4 * q2;
        outb[(size_t)o * HW + n] = acc[reg] + def_b[g * 64 + o];
    }
}

// ---------------------------------------------------------------------------
// Fallback (no workspace): round-1-style fused fp32 kernel, known correct.
// ---------------------------------------------------------------------------
__global__ __launch_bounds__(256, 4)
void deform_fallback(const float* __restrict__ x,
                     const float* __restrict__ off_w,
                     const float* __restrict__ off_b,
                     const float* __restrict__ def_w,
                     const float* __restrict__ def_b,
                     float* __restrict__ out)
{
    const int raw = blockIdx.x;
    const int r8  = raw & 7;
    const int h   = (raw >> 3) & 63;
    const int q8  = raw >> 9;
    const int bg  = q8 * 8 + r8;
    const int b   = bg >> 2;
    const int g   = bg & 3;

    __shared__ float pys[KK][W_];
    __shared__ float pxs[KK][W_];
    __shared__ float buf[8192];
    float* red   = buf;
    float* s_lds = buf;
    float* dwTl  = buf + 4096;

    const int t = threadIdx.x;
    const int w = t & 63;
    const int p = t >> 6;

    const float* xg = x + (size_t)(b * 256 + g * 64) * HW;

    float acc[18];
#pragma unroll
    for (int j = 0; j < 18; j++) acc[j] = 0.0f;
    {
        const int i0 = p * 16;
        for (int ii = 0; ii < 16; ii++) {
            const int i = i0 + ii;
            const float* xi = xg + i * HW;
#pragma unroll
            for (int r = 0; r < 3; r++) {
                const int y = h + r - 1;
                if ((unsigned)y >= (unsigned)H_) continue;
#pragma unroll
                for (int c = 0; c < 3; c++) {
                    const int xc = w + c - 1;
                    const float xv = ((unsigned)xc < (unsigned)W_) ? xi[y * W_ + xc] : 0.0f;
#pragma unroll
                    for (int j = 0; j < 18; j++) {
                        const float wv = off_w[((g * 18 + j) * CG + i) * 9 + r * 3 + c];
                        acc[j] = fmaf(wv, xv, acc[j]);
                    }
                }
            }
        }
    }
#pragma unroll
    for (int j = 0; j < 18; j++) red[(p * 18 + j) * 64 + w] = acc[j];
    __syncthreads();
    for (int idx = t; idx < 18 * 64; idx += 256) {
        const int j  = idx >> 6;
        const int ww = idx & 63;
        float v = red[(0 * 18 + j) * 64 + ww] + red[(1 * 18 + j) * 64 + ww]
                + red[(2 * 18 + j) * 64 + ww] + red[(3 * 18 + j) * 64 + ww];
        v += off_b[g * 18 + j];
        const int k = j >> 1;
        if ((j & 1) == 0) pys[k][ww] = v + (float)(k / 3 - 1) + (float)h;
        else              pxs[k][ww] = v + (float)(k % 3 - 1) + (float)ww;
    }
    __syncthreads();

    float facc[16];
#pragma unroll
    for (int qd = 0; qd < 16; qd++) facc[qd] = 0.0f;
    const int w4 = (t & 15) << 2;
    const int o4 = (t >> 4) << 2;

    for (int k = 0; k < KK; k++) {
#pragma unroll
        for (int n = 0; n < 16; n++) {
            const int v = t + 256 * n;
            const int i = v >> 6;
            const int o = v & 63;
            dwTl[v] = def_w[((g * CG + o) * CG + i) * KK + k];
        }
        const float py  = pys[k][w];
        const float px  = pxs[k][w];
        const float y0f = floorf(py);
        const float x0f = floorf(px);
        const float wy  = py - y0f;
        const float wx  = px - x0f;
        const int   y0  = (int)y0f;
        const int   x0  = (int)x0f;
        const float w00 = (1.0f - wy) * (1.0f - wx);
        const float w01 = (1.0f - wy) * wx;
        const float w10 = wy * (1.0f - wx);
        const float w11 = wy * wx;
        const bool vy0 = (unsigned)y0       < (unsigned)H_;
        const bool vy1 = (unsigned)(y0 + 1) < (unsigned)H_;
        const bool vx0 = (unsigned)x0       < (unsigned)W_;
        const bool vx1 = (unsigned)(x0 + 1) < (unsigned)W_;
        const int a00 = y0 * W_ + x0;
#pragma unroll
        for (int n = 0; n < 16; n++) {
            const int i = (n << 2) + p;
            const float* xi = xg + i * HW;
            const float v00 = (vy0 && vx0) ? xi[a00]          : 0.0f;
            const float v01 = (vy0 && vx1) ? xi[a00 + 1]      : 0.0f;
            const float v10 = (vy1 && vx0) ? xi[a00 + W_]     : 0.0f;
            const float v11 = (vy1 && vx1) ? xi[a00 + W_ + 1] : 0.0f;
            s_lds[i * 64 + w] = w00 * v00 + w01 * v01 + w10 * v10 + w11 * v11;
        }
        __syncthreads();
#pragma unroll 4
        for (int i = 0; i < CG; i++) {
            const float4 sv = *(const float4*)&s_lds[i * 64 + w4];
            const float4 dv = *(const float4*)&dwTl[i * 64 + o4];
            facc[0]  = fmaf(dv.x, sv.x, facc[0]);
            facc[1]  = fmaf(dv.x, sv.y, facc[1]);
            facc[2]  = fmaf(dv.x, sv.z, facc[2]);
            facc[3]  = fmaf(dv.x, sv.w, facc[3]);
            facc[4]  = fmaf(dv.y, sv.x, facc[4]);
            facc[5]  = fmaf(dv.y, sv.y, facc[5]);
            facc[6]  = fmaf(dv.y, sv.z, facc[6]);
            facc[7]  = fmaf(dv.y, sv.w, facc[7]);
            facc[8]  = fmaf(dv.z, sv.x, facc[8]);
            facc[9]  = fmaf(dv.z, sv.y, facc[9]);
            facc[10] = fmaf(dv.z, sv.z, facc[10]);
            facc[11] = fmaf(dv.z, sv.w, facc[11]);
            facc[12] = fmaf(dv.w, sv.x, facc[12]);
            facc[13] = fmaf(dv.w, sv.y, facc[13]);
            facc[14] = fmaf(dv.w, sv.z, facc[14]);
            facc[15] = fmaf(dv.w, sv.w, facc[15]);
        }
        __syncthreads();
    }

    float* outp = out + (size_t)(b * 256 + g * 64) * HW + h * W_;
#pragma unroll
    for (int oo = 0; oo < 4; oo++) {
        const int o = o4 + oo;
        const float bias = def_b[g * 64 + o];
        float4 r;
        r.x = facc[oo * 4 + 0] + bias;
        r.y = facc[oo * 4 + 1] + bias;
        r.z = facc[oo * 4 + 2] + bias;
        r.w = facc[oo * 4 + 3] + bias;
        *(float4*)&outp[o * HW + w4] = r;
    }
}

// ---------------------------------------------------------------------------
extern "C" void kernel_launch(void* const* d_in, const int* in_sizes, int n_in,
                              void* d_out, int out_size, void* d_ws, size_t ws_size,
                              hipStream_t stream)
{
    (void)in_sizes; (void)n_in; (void)out_size;
    const float* x     = (const float*)d_in[0];
    const float* off_w = (const float*)d_in[1];
    const float* off_b = (const float*)d_in[2];
    const float* def_w = (const float*)d_in[3];
    const float* def_b = (const float*)d_in[4];
    float* out = (float*)d_out;

    const size_t xT_bytes  = (size_t)B_ * G_ * XSLICE * 2;     // 37,879,808
    const size_t dw_bytes  = (size_t)G_ * KK * 4096 * 2;       // 294,912
    const size_t ow_bytes  = (size_t)G_ * 18 * 1024 * 2;       // 147,456
    const size_t need = xT_bytes + dw_bytes + ow_bytes;

    const int nblk   = B_ * G_ * H_;                     // 4096
    const int nprepw = (G_ * KK * 4096 + G_ * 18 * 1024 + 255) / 256;  // 864
    const int nprep  = 1024 + 64 + nprepw;               // x-tiles + zero rows + weights

    if (ws_size >= need) {
        short* xTpad = (short*)d_ws;
        short* dwA32 = (short*)((char*)d_ws + xT_bytes);
        short* owA   = (short*)((char*)d_ws + xT_bytes + dw_bytes);
        prep_all<<<nprep, 256, 0, stream>>>(x, off_w, def_w, xTpad, dwA32, owA);
        deform_main<<<nblk, 256, 0, stream>>>(xTpad, off_b, def_b, dwA32, owA, out);
    } else {
        deform_fallback<<<nblk, 256, 0, stream>>>(x, off_w, off_b, def_w, def_b, out);
    }
}

// Round 2
// 220.978 us; speedup vs baseline: 1.0172x; 1.0172x over previous
//
#include <hip/hip_runtime.h>
#include <hip/hip_bf16.h>
#include <hip/hip_fp16.h>

#define B_  16
#define G_  4
#define CG  64
#define H_  64
#define W_  64
#define KK  9
#define HW  (H_ * W_)
#define IP  72            // padded i-stride (shorts) for sT rows: 144 B
#define PD  68            // padded spatial dim (64 + 2 each side)
#define XSLICE (PD * PD * CG)   // shorts per (b,g) slice of xTpad

typedef short    short8  __attribute__((ext_vector_type(8)));
typedef _Float16 half8   __attribute__((ext_vector_type(8)));
typedef _Float16 h2      __attribute__((ext_vector_type(2)));
typedef float    f32x4   __attribute__((ext_vector_type(4)));
typedef float    f32x16  __attribute__((ext_vector_type(16)));

__device__ __forceinline__ short f2h(float v) {
    _Float16 h = (_Float16)v;
    short s;
    __builtin_memcpy(&s, &h, 2);
    return s;
}

__device__ __forceinline__ unsigned int pk2h(float a, float b) {
    h2 h = { (_Float16)a, (_Float16)b };
    unsigned int u;
    __builtin_memcpy(&u, &h, 4);
    return u;
}

// bilinear combine of 2 packed fp16 channels via native v_pk_fma_f16
__device__ __forceinline__ unsigned int interp2h(unsigned int c00, unsigned int c01,
                                                 unsigned int c10, unsigned int c11,
                                                 h2 w00, h2 w01, h2 w10, h2 w11) {
    h2 v00, v01, v10, v11;
    __builtin_memcpy(&v00, &c00, 4);
    __builtin_memcpy(&v01, &c01, 4);
    __builtin_memcpy(&v10, &c10, 4);
    __builtin_memcpy(&v11, &c11, 4);
    h2 r = v00 * w00 + v01 * w01 + v10 * w10 + v11 * w11;
    unsigned int o;
    __builtin_memcpy(&o, &r, 4);
    return o;
}

// ---------------------------------------------------------------------------
// Merged prep kernel (fp16 staging).
//  blocks [0, 1024): interior x transpose. Block = (bg, 4-row y-tile).
//  blocks [1024, 1088): y-border zero rows (yp in {0,1,66,67}) per bg.
//  blocks [1088, +864): weight prep
//   dwA32[g][k][mt][step][q2][o][e] f16 = def_w[g][mt*32+o][i=step*16+q2*8+e][k]
//   owA  [g][s][tm][q][jj][e]  f16 = off_w[g][j=tm*16+jj][(s&1)*32+q*8+e][s>>1]
// ---------------------------------------------------------------------------
__global__ __launch_bounds__(256)
void prep_all(const float* __restrict__ x,
              const float* __restrict__ off_w,
              const float* __restrict__ def_w,
              short* __restrict__ xTpad,
              short* __restrict__ dwA32,
              short* __restrict__ owA)
{
    const int blk = blockIdx.x;
    const int t   = threadIdx.x;

    if (blk < 1024) {
        const int bg = blk >> 4;
        const int y0 = (blk & 15) * 4;

        __shared__ unsigned int sBw[4 * CG * 33];   // 33792 B, f16x2 packed, padded

        const float* src = x + (size_t)bg * CG * HW + (size_t)y0 * W_;
        const int i  = t >> 2;          // channel 0..63
        const int x0 = (t & 3) * 16;    // col base 0/16/32/48

        // ---- load phase: 16 independent float4 loads per thread ----
        float4 v[4][4];
#pragma unroll
        for (int r = 0; r < 4; r++) {
            const float* sp = src + (size_t)i * HW + r * W_ + x0;
#pragma unroll
            for (int c = 0; c < 4; c++) v[r][c] = ((const float4*)sp)[c];
        }

        // ---- convert + stage (packed f16x2, padded row stride 33 words) ----
#pragma unroll
        for (int r = 0; r < 4; r++) {
#pragma unroll
            for (int c = 0; c < 4; c++) {
                const unsigned int u0 = pk2h(v[r][c].x, v[r][c].y);
                const unsigned int u1 = pk2h(v[r][c].z, v[r][c].w);
                const int base = (r * CG + i) * 33 + ((x0 + 4 * c) >> 1);
                sBw[base]     = u0;
                sBw[base + 1] = u1;
            }
        }
        __syncthreads();

        // ---- transpose-out phase: 16B stores, column reads hit 8 banks ----
        const short* sBs = (const short*)sBw;
        short* dst = xTpad + (size_t)bg * XSLICE;
#pragma unroll
        for (int r = 0; r < 4; r++) {
            const int yp = y0 + 2 + r;
            for (int task = t; task < PD * 8; task += 256) {
                const int ich = task & 7;
                const int xp  = task >> 3;
                const int xx  = xp - 2;
                short8 o = {0, 0, 0, 0, 0, 0, 0, 0};
                if ((unsigned)xx < (unsigned)W_) {
#pragma unroll
                    for (int e = 0; e < 8; e++)
                        o[e] = sBs[(r * CG + ich * 8 + e) * 66 + xx];
                }
                *(short8*)(dst + ((size_t)yp * PD + xp) * CG + ich * 8) = o;
            }
        }
        return;
    }

    if (blk < 1088) {
        // y-border zero rows: yp in {0,1} and {66,67}
        const int bg = blk - 1024;
        short* dstb = xTpad + (size_t)bg * XSLICE;
        const int4 z = {0, 0, 0, 0};
        int4* d0 = (int4*)(dstb);
        int4* d1 = (int4*)(dstb + (size_t)66 * PD * CG);
        const int n16 = (2 * PD * CG * 2) / 16;   // 1088 int4 per 2-row band
        for (int c = t; c < n16; c += 256) { d0[c] = z; d1[c] = z; }
        return;
    }

    // ---- weights part ----
    const int tid = (blk - 1088) * 256 + t;
    const int ndw = G_ * KK * 4096;               // 147456
    const int now = G_ * 18 * 2 * 4 * 16 * 8;     // 73728
    if (tid < ndw) {
        const int e    = tid & 7;
        const int o    = (tid >> 3) & 31;
        const int q2   = (tid >> 8) & 1;
        const int step = (tid >> 9) & 3;
        const int mt   = (tid >> 11) & 1;
        const int gk   = tid >> 12;
        const int k    = gk % KK;
        const int g    = gk / KK;
        const int oo   = mt * 32 + o;
        const int i    = step * 16 + q2 * 8 + e;
        dwA32[tid] = f2h(def_w[((g * CG + oo) * CG + i) * KK + k]);
    } else if (tid < ndw + now) {
        const int t2 = tid - ndw;
        const int e  = t2 & 7;
        const int jj = (t2 >> 3) & 15;
        const int q  = (t2 >> 7) & 3;
        const int tm = (t2 >> 9) & 1;
        const int gs = t2 >> 10;
        const int s  = gs % 18;
        const int g  = gs / 18;
        const int j  = tm * 16 + jj;
        const int rc = s >> 1;
        const int i  = (s & 1) * 32 + q * 8 + e;
        owA[t2] = (j < 18) ? f2h(off_w[((g * 18 + j) * CG + i) * KK + rc]) : (short)0;
    }
}

// ---------------------------------------------------------------------------
// Main fused kernel (fp16). Block = (b, g, h) with XCD swizzle. 256 thr, 4 waves.
//  Phase A: offset conv via MFMA 16x16x32 f16, coords -> pcs[9][64] float2.
//  Phase B: per tap: 16B-wide f16 gather from xTpad -> sT (double-buffered,
//           packed v_pk_fma_f16 interpolation), einsum via MFMA 32x32x16 f16.
// ---------------------------------------------------------------------------
__global__ __launch_bounds__(256, 7)
void deform_main(const short* __restrict__ xTpad,
                 const float* __restrict__ off_b,
                 const float* __restrict__ def_b,
                 const short* __restrict__ dwA32,
                 const short* __restrict__ owA,
                 float* __restrict__ out)
{
    const int raw = blockIdx.x;
    const int r8  = raw & 7;
    const int h   = (raw >> 3) & 63;
    const int q8  = raw >> 9;
    const int bg  = q8 * 8 + r8;
    const int b   = bg >> 2;
    const int g   = bg & 3;

    __shared__ float2 pcs[KK][64];          // .x = padded py, .y = padded px
    __shared__ short  sT[2][64 * IP];

    const int t    = threadIdx.x;
    const int lane = t & 63;
    const int p    = t >> 6;          // wave id 0..3
    const int nn   = lane & 15;
    const int q    = lane >> 4;

    const short* xb = xTpad + (size_t)bg * XSLICE;

    // ---------------- Phase A: offset conv (MFMA 16x16x32 f16) ----------------
    {
        const short* owAg = owA + g * 18 * 1024;
        f32x4 oa0 = {0.f, 0.f, 0.f, 0.f};
        f32x4 oa1 = {0.f, 0.f, 0.f, 0.f};
#pragma unroll
        for (int rc = 0; rc < 9; rc++) {
            const int rr = rc / 3;
            const int cc = rc % 3;
            const short* cp = xb + ((h + rr + 1) * PD + (p * 16 + nn + cc + 1)) * CG + q * 8;
            const half8 b0 = *(const half8*)cp;          // s = 2rc   (ih=0)
            const half8 b1 = *(const half8*)(cp + 32);   // s = 2rc+1 (ih=32)
            const int s0 = rc * 2, s1 = rc * 2 + 1;
            const half8 a00 = *(const half8*)(owAg + ((s0 * 2 + 0) * 4 + q) * 128 + nn * 8);
            const half8 a01 = *(const half8*)(owAg + ((s0 * 2 + 1) * 4 + q) * 128 + nn * 8);
            const half8 a10 = *(const half8*)(owAg + ((s1 * 2 + 0) * 4 + q) * 128 + nn * 8);
            const half8 a11 = *(const half8*)(owAg + ((s1 * 2 + 1) * 4 + q) * 128 + nn * 8);
            oa0 = __builtin_amdgcn_mfma_f32_16x16x32_f16(a00, b0, oa0, 0, 0, 0);
            oa1 = __builtin_amdgcn_mfma_f32_16x16x32_f16(a01, b0, oa1, 0, 0, 0);
            oa0 = __builtin_amdgcn_mfma_f32_16x16x32_f16(a10, b1, oa0, 0, 0, 0);
            oa1 = __builtin_amdgcn_mfma_f32_16x16x32_f16(a11, b1, oa1, 0, 0, 0);
        }
        // C layout: col = nn (w within tile), row = q*4 + reg (j)
        const int n = p * 16 + nn;
#pragma unroll
        for (int reg = 0; reg < 4; reg++) {
            const int j  = q * 4 + reg;
            const int kk = j >> 1;
            const float v = oa0[reg] + off_b[g * 18 + j];
            if ((j & 1) == 0) pcs[kk][n].x = v + (float)(kk / 3) + (float)(h + 1);
            else              pcs[kk][n].y = v + (float)(kk % 3) + (float)(n + 1);
        }
        if (q == 0) {
            pcs[8][n].x = oa1[0] + off_b[g * 18 + 16] + 2.0f + (float)(h + 1);
            pcs[8][n].y = oa1[1] + off_b[g * 18 + 17] + 2.0f + (float)(n + 1);
        }
        // each wave reads only its own tile's coords in the gather: no barrier
    }

    // ---------------- Phase B: gather + einsum, double-buffered ----------------
    const int mt  = p >> 1;           // einsum output 32-row tile
    const int nt  = p & 1;            // einsum output 32-col tile
    const int n31 = lane & 31;
    const int q2  = lane >> 5;

    f32x16 acc = {0.f};
    const short* dwg = dwA32 + g * KK * 4096;

    const int posL  = lane >> 3;      // 0..7: position within 8-group
    const int chidx = lane & 7;       // 8-channel chunk

    // gather of one tap into buffer sTb: 8 lanes/pos, 8 ch/lane, 16B loads
    auto gather_tap = [&](int k, short* __restrict__ sTb) {
#pragma unroll
        for (int it = 0; it < 2; it++) {
            const int pos = p * 16 + it * 8 + posL;
            const float2 pc = pcs[k][pos];
            const float yf = floorf(pc.x);
            const float xf = floorf(pc.y);
            const float wy = pc.x - yf;
            const float wx = pc.y - xf;
            int y0 = (int)yf;
            int x0 = (int)xf;
            y0 = (y0 < 0) ? 0 : ((y0 > 66) ? 66 : y0);
            x0 = (x0 < 0) ? 0 : ((x0 > 66) ? 66 : x0);
            const short* cp = xb + (y0 * PD + x0) * CG + chidx * 8;
            const uint4 c00 = *(const uint4*)cp;
            const uint4 c01 = *(const uint4*)(cp + CG);
            const uint4 c10 = *(const uint4*)(cp + PD * CG);
            const uint4 c11 = *(const uint4*)(cp + PD * CG + CG);
            const float a00 = (1.0f - wy) * (1.0f - wx);
            const float a01 = (1.0f - wy) * wx;
            const float a10 = wy * (1.0f - wx);
            const float a11 = wy * wx;
            const h2 w00 = { (_Float16)a00, (_Float16)a00 };
            const h2 w01 = { (_Float16)a01, (_Float16)a01 };
            const h2 w10 = { (_Float16)a10, (_Float16)a10 };
            const h2 w11 = { (_Float16)a11, (_Float16)a11 };
            uint4 ov;
            ov.x = interp2h(c00.x, c01.x, c10.x, c11.x, w00, w01, w10, w11);
            ov.y = interp2h(c00.y, c01.y, c10.y, c11.y, w00, w01, w10, w11);
            ov.z = interp2h(c00.z, c01.z, c10.z, c11.z, w00, w01, w10, w11);
            ov.w = interp2h(c00.w, c01.w, c10.w, c11.w, w00, w01, w10, w11);
            *(uint4*)&sTb[pos * IP + chidx * 8] = ov;
        }
    };

    // einsum of one tap from buffer sTb (MFMA 32x32x16 f16)
    auto einsum_tap = [&](int k, const short* __restrict__ sTb) {
        const short* dwk = dwg + k * 4096;
#pragma unroll
        for (int step = 0; step < 4; step++) {
            const half8 af = *(const half8*)(dwk + ((mt * 4 + step) * 2 + q2) * 256 + n31 * 8);
            const half8 bf = *(const half8*)&sTb[(nt * 32 + n31) * IP + step * 16 + q2 * 8];
            acc = __builtin_amdgcn_mfma_f32_32x32x16_f16(af, bf, acc, 0, 0, 0);
        }
    };

    gather_tap(0, &sT[0][0]);
    __syncthreads();
    for (int k = 0; k < KK; k++) {
        if (k < KK - 1) gather_tap(k + 1, &sT[(k + 1) & 1][0]);
        einsum_tap(k, &sT[k & 1][0]);
        __syncthreads();
    }

    // ---------------- epilogue ----------------
    // C/D 32x32 layout: col = lane&31, row = (reg&3) + 8*(reg>>2) + 4*q2
    float* outb = out + (size_t)(b * 256 + g * 64) * HW + h * W_;
    const int n = nt * 32 + n31;
#pragma unroll
    for (int reg = 0; reg < 16; reg++) {
        const int o = mt * 32 + (reg & 3) + 8 * (reg >> 2) + 4 * q2;
        outb[(size_t)o * HW + n] = acc[reg] + def_b[g * 64 + o];
    }
}

// ---------------------------------------------------------------------------
// Fallback (no workspace): round-1-style fused fp32 kernel, known correct.
// ---------------------------------------------------------------------------
__global__ __launch_bounds__(256, 4)
void deform_fallback(const float* __restrict__ x,
                     const float* __restrict__ off_w,
                     const float* __restrict__ off_b,
                     const float* __restrict__ def_w,
                     const float* __restrict__ def_b,
                     float* __restrict__ out)
{
    const int raw = blockIdx.x;
    const int r8  = raw & 7;
    const int h   = (raw >> 3) & 63;
    const int q8  = raw >> 9;
    const int bg  = q8 * 8 + r8;
    const int b   = bg >> 2;
    const int g   = bg & 3;

    __shared__ float pys[KK][W_];
    __shared__ float pxs[KK][W_];
    __shared__ float buf[8192];
    float* red   = buf;
    float* s_lds = buf;
    float* dwTl  = buf + 4096;

    const int t = threadIdx.x;
    const int w = t & 63;
    const int p = t >> 6;

    const float* xg = x + (size_t)(b * 256 + g * 64) * HW;

    float acc[18];
#pragma unroll
    for (int j = 0; j < 18; j++) acc[j] = 0.0f;
    {
        const int i0 = p * 16;
        for (int ii = 0; ii < 16; ii++) {
            const int i = i0 + ii;
            const float* xi = xg + i * HW;
#pragma unroll
            for (int r = 0; r < 3; r++) {
                const int y = h + r - 1;
                if ((unsigned)y >= (unsigned)H_) continue;
#pragma unroll
                for (int c = 0; c < 3; c++) {
                    const int xc = w + c - 1;
                    const float xv = ((unsigned)xc < (unsigned)W_) ? xi[y * W_ + xc] : 0.0f;
#pragma unroll
                    for (int j = 0; j < 18; j++) {
                        const float wv = off_w[((g * 18 + j) * CG + i) * 9 + r * 3 + c];
                        acc[j] = fmaf(wv, xv, acc[j]);
                    }
                }
            }
        }
    }
#pragma unroll
    for (int j = 0; j < 18; j++) red[(p * 18 + j) * 64 + w] = acc[j];
    __syncthreads();
    for (int idx = t; idx < 18 * 64; idx += 256) {
        const int j  = idx >> 6;
        const int ww = idx & 63;
        float v = red[(0 * 18 + j) * 64 + ww] + red[(1 * 18 + j) * 64 + ww]
                + red[(2 * 18 + j) * 64 + ww] + red[(3 * 18 + j) * 64 + ww];
        v += off_b[g * 18 + j];
        const int k = j >> 1;
        if ((j & 1) == 0) pys[k][ww] = v + (float)(k / 3 - 1) + (float)h;
        else              pxs[k][ww] = v + (float)(k % 3 - 1) + (float)ww;
    }
    __syncthreads();

    float facc[16];
#pragma unroll
    for (int qd = 0; qd < 16; qd++) facc[qd] = 0.0f;
    const int w4 = (t & 15) << 2;
    const int o4 = (t >> 4) << 2;

    for (int k = 0; k < KK; k++) {
#pragma unroll
        for (int n = 0; n < 16; n++) {
            const int v = t + 256 * n;
            const int i = v >> 6;
            const int o = v & 63;
            dwTl[v] = def_w[((g * CG + o) * CG + i) * KK + k];
        }
        const float py  = pys[k][w];
        const float px  = pxs[k][w];
        const float y0f = floorf(py);
        const float x0f = floorf(px);
        const float wy  = py - y0f;
        const float wx  = px - x0f;
        const int   y0  = (int)y0f;
        const int   x0  = (int)x0f;
        const float w00 = (1.0f - wy) * (1.0f - wx);
        const float w01 = (1.0f - wy) * wx;
        const float w10 = wy * (1.0f - wx);
        const float w11 = wy * wx;
        const bool vy0 = (unsigned)y0       < (unsigned)H_;
        const bool vy1 = (unsigned)(y0 + 1) < (unsigned)H_;
        const bool vx0 = (unsigned)x0       < (unsigned)W_;
        const bool vx1 = (unsigned)(x0 + 1) < (unsigned)W_;
        const int a00 = y0 * W_ + x0;
#pragma unroll
        for (int n = 0; n < 16; n++) {
            const int i = (n << 2) + p;
            const float* xi = xg + i * HW;
            const float v00 = (vy0 && vx0) ? xi[a00]          : 0.0f;
            const float v01 = (vy0 && vx1) ? xi[a00 + 1]      : 0.0f;
            const float v10 = (vy1 && vx0) ? xi[a00 + W_]     : 0.0f;
            const float v11 = (vy1 && vx1) ? xi[a00 + W_ + 1] : 0.0f;
            s_lds[i * 64 + w] = w00 * v00 + w01 * v01 + w10 * v10 + w11 * v11;
        }
        __syncthreads();
#pragma unroll 4
        for (int i = 0; i < CG; i++) {
            const float4 sv = *(const float4*)&s_lds[i * 64 + w4];
            const float4 dv = *(const float4*)&dwTl[i * 64 + o4];
            facc[0]  = fmaf(dv.x, sv.x, facc[0]);
            facc[1]  = fmaf(dv.x, sv.y, facc[1]);
            facc[2]  = fmaf(dv.x, sv.z, facc[2]);
            facc[3]  = fmaf(dv.x, sv.w, facc[3]);
            facc[4]  = fmaf(dv.y, sv.x, facc[4]);
            facc[5]  = fmaf(dv.y, sv.y, facc[5]);
            facc[6]  = fmaf(dv.y, sv.z, facc[6]);
            facc[7]  = fmaf(dv.y, sv.w, facc[7]);
            facc[8]  = fmaf(dv.z, sv.x, facc[8]);
            facc[9]  = fmaf(dv.z, sv.y, facc[9]);
            facc[10] = fmaf(dv.z, sv.z, facc[10]);
            facc[11] = fmaf(dv.z, sv.w, facc[11]);
            facc[12] = fmaf(dv.w, sv.x, facc[12]);
            facc[13] = fmaf(dv.w, sv.y, facc[13]);
            facc[14] = fmaf(dv.w, sv.z, facc[14]);
            facc[15] = fmaf(dv.w, sv.w, facc[15]);
        }
        __syncthreads();
    }

    float* outp = out + (size_t)(b * 256 + g * 64) * HW + h * W_;
#pragma unroll
    for (int oo = 0; oo < 4; oo++) {
        const int o = o4 + oo;
        const float bias = def_b[g * 64 + o];
        float4 r;
        r.x = facc[oo * 4 + 0] + bias;
        r.y = facc[oo * 4 + 1] + bias;
        r.z = facc[oo * 4 + 2] + bias;
        r.w = facc[oo * 4 + 3] + bias;
        *(float4*)&outp[o * HW + w4] = r;
    }
}

// ---------------------------------------------------------------------------
extern "C" void kernel_launch(void* const* d_in, const int* in_sizes, int n_in,
                              void* d_out, int out_size, void* d_ws, size_t ws_size,
                              hipStream_t stream)
{
    (void)in_sizes; (void)n_in; (void)out_size;
    const float* x     = (const float*)d_in[0];
    const float* off_w = (const float*)d_in[1];
    const float* off_b = (const float*)d_in[2];
    const float* def_w = (const float*)d_in[3];
    const float* def_b = (const float*)d_in[4];
    float* out = (float*)d_out;

    const size_t xT_bytes  = (size_t)B_ * G_ * XSLICE * 2;     // 37,879,808
    const size_t dw_bytes  = (size_t)G_ * KK * 4096 * 2;       // 294,912
    const size_t ow_bytes  = (size_t)G_ * 18 * 1024 * 2;       // 147,456
    const size_t need = xT_bytes + dw_bytes + ow_bytes;

    const int nblk   = B_ * G_ * H_;                     // 4096
    const int nprepw = (G_ * KK * 4096 + G_ * 18 * 1024 + 255) / 256;  // 864
    const int nprep  = 1024 + 64 + nprepw;               // x-tiles + zero rows + weights

    if (ws_size >= need) {
        short* xTpad = (short*)d_ws;
        short* dwA32 = (short*)((char*)d_ws + xT_bytes);
        short* owA   = (short*)((char*)d_ws + xT_bytes + dw_bytes);
        prep_all<<<nprep, 256, 0, stream>>>(x, off_w, def_w, xTpad, dwA32, owA);
        deform_main<<<nblk, 256, 0, stream>>>(xTpad, off_b, def_b, dwA32, owA, out);
    } else {
        deform_fallback<<<nblk, 256, 0, stream>>>(x, off_w, off_b, def_w, def_b, out);
    }
}